// Round 5
// baseline (564.020 us; speedup 1.0000x reference)
//
#include <hip/hip_runtime.h>

typedef _Float16 f16;
typedef _Float16 f16x8 __attribute__((ext_vector_type(8)));
typedef _Float16 f16x4 __attribute__((ext_vector_type(4)));
typedef float    f32x4 __attribute__((ext_vector_type(4)));

#define DEV __device__ __forceinline__

// ---------- helpers ----------
DEV void gload16(const void* g, void* l) {
  __builtin_amdgcn_global_load_lds(
      (const __attribute__((address_space(1))) unsigned int*)g,
      (__attribute__((address_space(3))) unsigned int*)l, 16, 0, 0);
}
DEV float rmax16(float v) {
  v = fmaxf(v, __shfl_xor(v, 1));
  v = fmaxf(v, __shfl_xor(v, 2));
  v = fmaxf(v, __shfl_xor(v, 4));
  v = fmaxf(v, __shfl_xor(v, 8));
  return v;
}
DEV float rsum16(float v) {
  v += __shfl_xor(v, 1);
  v += __shfl_xor(v, 2);
  v += __shfl_xor(v, 4);
  v += __shfl_xor(v, 8);
  return v;
}

// ---------- elementwise f32 -> f16 cast ----------
__global__ void cast_f16(const float* __restrict__ s, f16* __restrict__ d, int n4) {
  int i = blockIdx.x * blockDim.x + threadIdx.x;
  if (i < n4) {
    float4 v = ((const float4*)s)[i];
    f16x4 o;
    o[0] = (f16)v.x; o[1] = (f16)v.y; o[2] = (f16)v.z; o[3] = (f16)v.w;
    ((f16x4*)d)[i] = o;
  }
}

// ---------- transpose + cast: src[R][C] f32 -> dst[C][R] f16 ----------
__global__ void transpose_cast(const float* __restrict__ src, f16* __restrict__ dst,
                               int R, int C) {
  __shared__ float tile[64][65];
  const int cb = blockIdx.x * 64, rb = blockIdx.y * 64;
  const int tx = threadIdx.x & 63, ty = threadIdx.x >> 6; // ty 0..3
#pragma unroll
  for (int i = 0; i < 64; i += 4)
    tile[ty + i][tx] = src[(size_t)(rb + ty + i) * C + cb + tx];
  __syncthreads();
#pragma unroll
  for (int i = 0; i < 64; i += 4)
    dst[(size_t)(cb + ty + i) * R + rb + tx] = (f16)tile[tx][ty + i];
}

// ---------- mask prep: build mpad[8][1024] u8 with CLS=1, format auto-detect ----------
__global__ void prep_mask(const void* __restrict__ mask, unsigned char* __restrict__ mpad) {
  int i = blockIdx.x * blockDim.x + threadIdx.x; // 0..8191
  if (i >= 8192) return;
  const unsigned int* wv = (const unsigned int*)mask;
  bool anyf32 = false, anybig = false;
  for (int k = 0; k < 64; k++) {
    unsigned int x = wv[k];
    if (x == 0x3f800000u) anyf32 = true;
    else if (x > 1u) anybig = true;
  }
  int b = i >> 10, j = i & 1023;
  bool v;
  if (j == 0) v = true;
  else {
    size_t idx = (size_t)b * 1023 + (j - 1);
    if (anyf32)      v = ((const float*)mask)[idx] != 0.f;
    else if (anybig) v = ((const unsigned char*)mask)[idx] != 0;
    else             v = ((const int*)mask)[idx] != 0;
  }
  mpad[i] = v ? 1 : 0;
}

// ---------- generic 128x128 f16 MFMA GEMM: C = A[M,K] * Bt[N,K]^T ----------
// MODE 0: qkv — cols<2048 -> qkb[b][n][2048]; cols>=2048 -> vTb[b][d][n] (transposed)
// MODE 1: pooled S — f32 * SCALE_ -> Cf (+z*sCb)
// MODE 2: out proj — f32 + bias -> Cf
template <int MODE>
__global__ __launch_bounds__(256, 2) void gemm_nt(
    const f16* __restrict__ A, int lda, long sAb,
    const f16* __restrict__ Bt, int ldb, long sBb,
    float* __restrict__ Cf, long sCb,
    const float* __restrict__ bias,
    f16* __restrict__ qkb, f16* __restrict__ vTb,
    int N, int K) {
  __shared__ __align__(16) f16 As[128 * 32];
  __shared__ __align__(16) f16 Bs[128 * 32];
  const int tid = threadIdx.x;
  const int w = tid >> 6, l = tid & 63;
  const int lr = l & 15, lg = l >> 4;
  const int wm = w >> 1, wn = w & 1;
  const int m0 = blockIdx.y * 128, n0 = blockIdx.x * 128;
  const int z = blockIdx.z;
  const f16* Ab = A + (size_t)z * sAb;
  const f16* Btb = Bt + (size_t)z * sBb;

  const f32x4 zero4 = {0.f, 0.f, 0.f, 0.f};
  f32x4 acc[4][4];
#pragma unroll
  for (int m = 0; m < 4; m++)
#pragma unroll
    for (int n = 0; n < 4; n++) acc[m][n] = zero4;

  const int srow = l >> 2;               // row within 16-row staging block
  const int sch = (l & 3) ^ (srow & 3);  // pre-swizzled source chunk (involution)

  for (int k0 = 0; k0 < K; k0 += 32) {
#pragma unroll
    for (int i = 0; i < 2; i++) {
      int blk = w * 2 + i; // 0..7, 16 rows each
      int row = blk * 16 + srow;
      gload16(Ab + (size_t)(m0 + row) * lda + k0 + sch * 8, (void*)(As + blk * 512));
      gload16(Btb + (size_t)(n0 + row) * ldb + k0 + sch * 8, (void*)(Bs + blk * 512));
    }
    __syncthreads();
    f16x8 af[4], bf[4];
#pragma unroll
    for (int m = 0; m < 4; m++) {
      int row = wm * 64 + m * 16 + lr;
      af[m] = *(const f16x8*)&As[row * 32 + ((lg ^ (row & 3)) << 3)];
    }
#pragma unroll
    for (int n = 0; n < 4; n++) {
      int row = wn * 64 + n * 16 + lr;
      bf[n] = *(const f16x8*)&Bs[row * 32 + ((lg ^ (row & 3)) << 3)];
    }
#pragma unroll
    for (int m = 0; m < 4; m++)
#pragma unroll
      for (int n = 0; n < 4; n++)
        acc[m][n] = __builtin_amdgcn_mfma_f32_16x16x32_f16(af[m], bf[n], acc[m][n], 0, 0, 0);
    __syncthreads();
  }

  // epilogue: C layout col = lane&15, row = (lane>>4)*4 + reg
#pragma unroll
  for (int m = 0; m < 4; m++) {
    const int rb0 = m0 + wm * 64 + m * 16 + lg * 4;
#pragma unroll
    for (int n = 0; n < 4; n++) {
      const int c = n0 + wn * 64 + n * 16 + lr;
      if constexpr (MODE == 0) {
        if (c < 2048) {
#pragma unroll
          for (int ri = 0; ri < 4; ri++) {
            int rr = rb0 + ri;
            qkb[(size_t)(rr >> 10) * 2097152 + (size_t)(rr & 1023) * 2048 + c] =
                (f16)acc[m][n][ri];
          }
        } else {
          int bb = rb0 >> 10, nn = rb0 & 1023;
          f16x4 pk;
#pragma unroll
          for (int ri = 0; ri < 4; ri++) pk[ri] = (f16)acc[m][n][ri];
          *(f16x4*)(vTb + (size_t)bb * 1048576 + (size_t)(c - 2048) * 1024 + nn) = pk;
        }
      } else if constexpr (MODE == 1) {
        float* Cz = Cf + (size_t)z * sCb;
#pragma unroll
        for (int ri = 0; ri < 4; ri++)
          Cz[(size_t)(rb0 + ri) * N + c] = acc[m][n][ri] * 0.03125f; // SCALE_
      } else {
        float bv = bias[c];
#pragma unroll
        for (int ri = 0; ri < 4; ri++)
          Cf[(size_t)(rb0 + ri) * N + c] = acc[m][n][ri] + bv;
      }
    }
  }
}

// ---------- row softmax in-place on [rows][1024] f32 ----------
__global__ __launch_bounds__(256) void softmax_rows(float* __restrict__ p) {
  __shared__ float redm[4], reds[4];
  float* row = p + (size_t)blockIdx.x * 1024;
  const int t = threadIdx.x;
  float4 v = ((const float4*)row)[t];
  float mx = fmaxf(fmaxf(v.x, v.y), fmaxf(v.z, v.w));
#pragma unroll
  for (int d = 1; d < 64; d <<= 1) mx = fmaxf(mx, __shfl_xor(mx, d));
  if ((t & 63) == 0) redm[t >> 6] = mx;
  __syncthreads();
  mx = fmaxf(fmaxf(redm[0], redm[1]), fmaxf(redm[2], redm[3]));
  v.x = __expf(v.x - mx); v.y = __expf(v.y - mx);
  v.z = __expf(v.z - mx); v.w = __expf(v.w - mx);
  float s = v.x + v.y + v.z + v.w;
#pragma unroll
  for (int d = 1; d < 64; d <<= 1) s += __shfl_xor(s, d);
  if ((t & 63) == 0) reds[t >> 6] = s;
  __syncthreads();
  s = reds[0] + reds[1] + reds[2] + reds[3];
  float inv = 1.0f / s;
  v.x *= inv; v.y *= inv; v.z *= inv; v.w *= inv;
  ((float4*)row)[t] = v;
}

// ---------- flash MHA: 4 waves x 64 q-rows, KVBLK=64, online softmax + mask ----------
__global__ __launch_bounds__(256, 2) void flash_kernel(
    const f16* __restrict__ qkb,   // [8][1024][2048] q|k
    const f16* __restrict__ vTb,   // [8][1024 d][1024 n]
    const unsigned char* __restrict__ mpad, // [8][1024]
    f16* __restrict__ ob) {        // [8192][1024]
  __shared__ __align__(16) f16 Ks[64 * 64];
  __shared__ __align__(16) f16 Vts[64 * 64];
  __shared__ __align__(16) f16 Ps[4][64 * 64];

  const int tid = threadIdx.x;
  const int w = tid >> 6, l = tid & 63;
  const int lr = l & 15, lg = l >> 4;
  const int qt = blockIdx.x, h = blockIdx.y, b = blockIdx.z;
  const int qbase = qt * 256 + w * 64;
  const f16* qk_b = qkb + (size_t)b * 2097152;
  const f16* vT_b = vTb + (size_t)b * 1048576 + (size_t)h * 64 * 1024;
  const unsigned char* mp = mpad + b * 1024;

  // Q fragments (A-layout: row = lane&15, k = (lane>>4)*8 + j)
  f16x8 qf[4][2];
#pragma unroll
  for (int m = 0; m < 4; m++)
#pragma unroll
    for (int kk = 0; kk < 2; kk++) {
      int row = qbase + m * 16 + lr;
      int col = h * 64 + kk * 32 + lg * 8;
      qf[m][kk] = *(const f16x8*)(qk_b + (size_t)row * 2048 + col);
    }

  // row mask bits (bit m*4+ri)
  unsigned int mi_bits = 0;
#pragma unroll
  for (int m = 0; m < 4; m++)
#pragma unroll
    for (int ri = 0; ri < 4; ri++)
      mi_bits |= (mp[qbase + m * 16 + lg * 4 + ri] ? 1u : 0u) << (m * 4 + ri);

  const f32x4 zero4 = {0.f, 0.f, 0.f, 0.f};
  float mrun[4][4], lrun[4][4];
  f32x4 oacc[4][4];
#pragma unroll
  for (int m = 0; m < 4; m++)
#pragma unroll
    for (int i = 0; i < 4; i++) {
      mrun[m][i] = -3e38f; lrun[m][i] = 0.f; oacc[m][i] = zero4;
    }

  const int srow = l >> 3;            // 0..7 staging row within 8-row block
  const int schunk = (l & 7) ^ srow;  // pre-swizzled source chunk

  for (int t = 0; t < 16; t++) {
    // stage K tile [64 tok][64 d] and V^T tile [64 d][64 tok], swizzled source
#pragma unroll
    for (int i = 0; i < 2; i++) {
      int blk = w * 2 + i; // 8 rows each
      int row = blk * 8 + srow;
      gload16(qk_b + 1024 + (size_t)(t * 64 + row) * 2048 + h * 64 + schunk * 8,
              (void*)(Ks + blk * 512));
      gload16(vT_b + (size_t)row * 1024 + t * 64 + schunk * 8,
              (void*)(Vts + blk * 512));
    }
    __syncthreads();

    // S = Q K^T
    f32x4 sacc[4][4];
#pragma unroll
    for (int m = 0; m < 4; m++)
#pragma unroll
      for (int n = 0; n < 4; n++) sacc[m][n] = zero4;
#pragma unroll
    for (int kk = 0; kk < 2; kk++)
#pragma unroll
      for (int n = 0; n < 4; n++) {
        int krow = n * 16 + lr;
        int ch = (kk * 4 + lg) ^ (krow & 7);
        f16x8 kf = *(const f16x8*)&Ks[krow * 64 + ch * 8];
#pragma unroll
        for (int m = 0; m < 4; m++)
          sacc[m][n] = __builtin_amdgcn_mfma_f32_16x16x32_f16(qf[m][kk], kf, sacc[m][n], 0, 0, 0);
      }

    unsigned int mj_bits = 0;
#pragma unroll
    for (int n = 0; n < 4; n++)
      mj_bits |= (mp[t * 64 + n * 16 + lr] ? 1u : 0u) << n;

    // online softmax + write P (swizzled per-wave LDS)
#pragma unroll
    for (int m = 0; m < 4; m++) {
#pragma unroll
      for (int ri = 0; ri < 4; ri++) {
        const bool rowok = (mi_bits >> (m * 4 + ri)) & 1;
        float sv[4];
        float vmax = -3e38f;
#pragma unroll
        for (int n = 0; n < 4; n++) {
          float s = sacc[m][n][ri];
          s = rowok ? (((mj_bits >> n) & 1) ? s * 0.125f : -1e30f) : 0.f;
          sv[n] = s;
          vmax = fmaxf(vmax, s);
        }
        vmax = rmax16(vmax);
        float nm = fmaxf(mrun[m][ri], vmax);
        float sc = __expf(mrun[m][ri] - nm); // 0 on first tile
        mrun[m][ri] = nm;
        float rs = 0.f;
        const int qr = m * 16 + lg * 4 + ri;
#pragma unroll
        for (int n = 0; n < 4; n++) {
          float pp = __expf(sv[n] - nm);
          rs += pp;
          int col = n * 16 + lr;
          Ps[w][qr * 64 + ((((col >> 3) ^ (qr & 7)) << 3)) + (col & 7)] = (f16)pp;
        }
        rs = rsum16(rs);
        lrun[m][ri] = lrun[m][ri] * sc + rs;
#pragma unroll
        for (int dn = 0; dn < 4; dn++) oacc[m][dn][ri] *= sc;
      }
    }
    asm volatile("s_waitcnt lgkmcnt(0)" ::: "memory");
    __builtin_amdgcn_sched_barrier(0);

    // O += P V   (A = P from Ps, B = rows of V^T from Vts)
#pragma unroll
    for (int kk = 0; kk < 2; kk++) {
      f16x8 pa[4];
#pragma unroll
      for (int m = 0; m < 4; m++) {
        int qr = m * 16 + lr;
        int ch = (kk * 4 + lg) ^ (qr & 7);
        pa[m] = *(const f16x8*)&Ps[w][qr * 64 + ch * 8];
      }
#pragma unroll
      for (int dn = 0; dn < 4; dn++) {
        int vrow = dn * 16 + lr;
        int ch = (kk * 4 + lg) ^ (vrow & 7);
        f16x8 vf = *(const f16x8*)&Vts[vrow * 64 + ch * 8];
#pragma unroll
        for (int m = 0; m < 4; m++)
          oacc[m][dn] = __builtin_amdgcn_mfma_f32_16x16x32_f16(pa[m], vf, oacc[m][dn], 0, 0, 0);
      }
    }
    __syncthreads();
  }

  // epilogue: O / l  -> ob f16
#pragma unroll
  for (int m = 0; m < 4; m++)
#pragma unroll
    for (int dn = 0; dn < 4; dn++)
#pragma unroll
      for (int ri = 0; ri < 4; ri++) {
        int qg = qbase + m * 16 + lg * 4 + ri;
        float o = oacc[m][dn][ri] / lrun[m][ri];
        ob[(size_t)(b * 1024 + qg) * 1024 + h * 64 + dn * 16 + lr] = (f16)o;
      }
}

// ---------- host ----------
extern "C" void kernel_launch(void* const* d_in, const int* in_sizes, int n_in,
                              void* d_out, int out_size, void* d_ws, size_t ws_size,
                              hipStream_t stream) {
  const float* x     = (const float*)d_in[0];
  const void*  mask  = d_in[1];
  const float* w_qkv = (const float*)d_in[2];
  const float* w_out = (const float*)d_in[3];
  const float* b_out = (const float*)d_in[4];
  float* out  = (float*)d_out;           // [8192][1024]
  float* attn = out + 8388608;           // [8][1024][1024]

  char* ws = (char*)d_ws;
  f16* xb    = (f16*)(ws);                    // [8192][1024]          16.78 MB (dead after gemm<0>)
  f16* wqkvT = (f16*)(ws + 16777216);         // [3072][1024]           6.29 MB
  f16* woutT = (f16*)(ws + 23068672);         // [1024][1024]           2.10 MB
  f16* qkb   = (f16*)(ws + 25165824);         // [8][1024][2048]       33.55 MB
  f16* vTb   = (f16*)(ws + 58720256);         // [8][1024 d][1024 n]   16.78 MB
  f16* ob    = xb;                            // aliases xb (lifetimes disjoint)
  unsigned char* mpad = (unsigned char*)(ws + 75497472); // [8][1024]

  cast_f16<<<8192, 256, 0, stream>>>(x, xb, 2097152);
  transpose_cast<<<dim3(48, 16), 256, 0, stream>>>(w_qkv, wqkvT, 1024, 3072);
  transpose_cast<<<dim3(16, 16), 256, 0, stream>>>(w_out, woutT, 1024, 1024);
  prep_mask<<<32, 256, 0, stream>>>(mask, mpad);

  // qkv = x @ w_qkv  (M=8192, N=3072, K=1024)
  gemm_nt<0><<<dim3(24, 64), 256, 0, stream>>>(xb, 1024, 0, wqkvT, 1024, 0,
                                               nullptr, 0, nullptr, qkb, vTb, 3072, 1024);
  // pooled S = q_ k_^T * SCALE_  (per batch, M=N=K=1024)
  gemm_nt<1><<<dim3(8, 8, 8), 256, 0, stream>>>(qkb, 2048, 2097152, qkb + 1024, 2048, 2097152,
                                                attn, 1048576, nullptr, nullptr, nullptr, 1024, 1024);
  softmax_rows<<<8192, 256, 0, stream>>>(attn);

  flash_kernel<<<dim3(4, 16, 8), 256, 0, stream>>>(qkb, vTb, mpad, ob);

  // out = ob @ w_out + b_out  (M=8192, N=1024, K=1024)
  gemm_nt<2><<<dim3(8, 64), 256, 0, stream>>>(ob, 1024, 0, woutT, 1024, 0,
                                              out, 0, b_out, nullptr, nullptr, 1024, 1024);
}

// Round 6
// 502.830 us; speedup vs baseline: 1.1217x; 1.1217x over previous
//
#include <hip/hip_runtime.h>

typedef _Float16 f16;
typedef _Float16 f16x8 __attribute__((ext_vector_type(8)));
typedef _Float16 f16x4 __attribute__((ext_vector_type(4)));
typedef float    f32x4 __attribute__((ext_vector_type(4)));

#define DEV __device__ __forceinline__

// ---------- helpers ----------
DEV void gload16(const void* g, void* l) {
  __builtin_amdgcn_global_load_lds(
      (const __attribute__((address_space(1))) unsigned int*)g,
      (__attribute__((address_space(3))) unsigned int*)l, 16, 0, 0);
}
DEV float rmax16(float v) {
  v = fmaxf(v, __shfl_xor(v, 1));
  v = fmaxf(v, __shfl_xor(v, 2));
  v = fmaxf(v, __shfl_xor(v, 4));
  v = fmaxf(v, __shfl_xor(v, 8));
  return v;
}
DEV float rsum16(float v) {
  v += __shfl_xor(v, 1);
  v += __shfl_xor(v, 2);
  v += __shfl_xor(v, 4);
  v += __shfl_xor(v, 8);
  return v;
}

// ---------- elementwise f32 -> f16 cast ----------
__global__ void cast_f16(const float* __restrict__ s, f16* __restrict__ d, int n4) {
  int i = blockIdx.x * blockDim.x + threadIdx.x;
  if (i < n4) {
    float4 v = ((const float4*)s)[i];
    f16x4 o;
    o[0] = (f16)v.x; o[1] = (f16)v.y; o[2] = (f16)v.z; o[3] = (f16)v.w;
    ((f16x4*)d)[i] = o;
  }
}

// ---------- transpose + cast: src[R][C] f32 -> dst[C][R] f16 ----------
__global__ void transpose_cast(const float* __restrict__ src, f16* __restrict__ dst,
                               int R, int C) {
  __shared__ float tile[64][65];
  const int cb = blockIdx.x * 64, rb = blockIdx.y * 64;
  const int tx = threadIdx.x & 63, ty = threadIdx.x >> 6; // ty 0..3
#pragma unroll
  for (int i = 0; i < 64; i += 4)
    tile[ty + i][tx] = src[(size_t)(rb + ty + i) * C + cb + tx];
  __syncthreads();
#pragma unroll
  for (int i = 0; i < 64; i += 4)
    dst[(size_t)(cb + ty + i) * R + rb + tx] = (f16)tile[tx][ty + i];
}

// ---------- mask prep: build mpad[8][1024] u8 with CLS=1, format auto-detect ----------
__global__ void prep_mask(const void* __restrict__ mask, unsigned char* __restrict__ mpad) {
  int i = blockIdx.x * blockDim.x + threadIdx.x; // 0..8191
  if (i >= 8192) return;
  const unsigned int* wv = (const unsigned int*)mask;
  bool anyf32 = false, anybig = false;
  for (int k = 0; k < 64; k++) {
    unsigned int x = wv[k];
    if (x == 0x3f800000u) anyf32 = true;
    else if (x > 1u) anybig = true;
  }
  int b = i >> 10, j = i & 1023;
  bool v;
  if (j == 0) v = true;
  else {
    size_t idx = (size_t)b * 1023 + (j - 1);
    if (anyf32)      v = ((const float*)mask)[idx] != 0.f;
    else if (anybig) v = ((const unsigned char*)mask)[idx] != 0;
    else             v = ((const int*)mask)[idx] != 0;
  }
  mpad[i] = v ? 1 : 0;
}

// ---------- generic 128x128 f16 MFMA GEMM: C = A[M,K] * Bt[N,K]^T ----------
// MODE 0: qkv — cols<2048 -> qkb[b][n][2048]; cols>=2048 -> vTb[b][d][n] (transposed)
// MODE 1: pooled S — f32 * SCALE_ -> Cf (+z*sCb)
// MODE 2: out proj — f32 + bias -> Cf
template <int MODE>
__global__ __launch_bounds__(256, 2) void gemm_nt(
    const f16* __restrict__ A, int lda, long sAb,
    const f16* __restrict__ Bt, int ldb, long sBb,
    float* __restrict__ Cf, long sCb,
    const float* __restrict__ bias,
    f16* __restrict__ qkb, f16* __restrict__ vTb,
    int N, int K) {
  __shared__ __align__(16) f16 As[128 * 32];
  __shared__ __align__(16) f16 Bs[128 * 32];
  const int tid = threadIdx.x;
  const int w = tid >> 6, l = tid & 63;
  const int lr = l & 15, lg = l >> 4;
  const int wm = w >> 1, wn = w & 1;
  const int m0 = blockIdx.y * 128, n0 = blockIdx.x * 128;
  const int z = blockIdx.z;
  const f16* Ab = A + (size_t)z * sAb;
  const f16* Btb = Bt + (size_t)z * sBb;

  const f32x4 zero4 = {0.f, 0.f, 0.f, 0.f};
  f32x4 acc[4][4];
#pragma unroll
  for (int m = 0; m < 4; m++)
#pragma unroll
    for (int n = 0; n < 4; n++) acc[m][n] = zero4;

  const int srow = l >> 2;               // row within 16-row staging block
  const int sch = (l & 3) ^ (srow & 3);  // pre-swizzled source chunk (involution)

  for (int k0 = 0; k0 < K; k0 += 32) {
#pragma unroll
    for (int i = 0; i < 2; i++) {
      int blk = w * 2 + i; // 0..7, 16 rows each
      int row = blk * 16 + srow;
      gload16(Ab + (size_t)(m0 + row) * lda + k0 + sch * 8, (void*)(As + blk * 512));
      gload16(Btb + (size_t)(n0 + row) * ldb + k0 + sch * 8, (void*)(Bs + blk * 512));
    }
    __syncthreads();
    f16x8 af[4], bf[4];
#pragma unroll
    for (int m = 0; m < 4; m++) {
      int row = wm * 64 + m * 16 + lr;
      af[m] = *(const f16x8*)&As[row * 32 + ((lg ^ (row & 3)) << 3)];
    }
#pragma unroll
    for (int n = 0; n < 4; n++) {
      int row = wn * 64 + n * 16 + lr;
      bf[n] = *(const f16x8*)&Bs[row * 32 + ((lg ^ (row & 3)) << 3)];
    }
#pragma unroll
    for (int m = 0; m < 4; m++)
#pragma unroll
      for (int n = 0; n < 4; n++)
        acc[m][n] = __builtin_amdgcn_mfma_f32_16x16x32_f16(af[m], bf[n], acc[m][n], 0, 0, 0);
    __syncthreads();
  }

  // epilogue: C layout col = lane&15, row = (lane>>4)*4 + reg
#pragma unroll
  for (int m = 0; m < 4; m++) {
    const int rb0 = m0 + wm * 64 + m * 16 + lg * 4;
#pragma unroll
    for (int n = 0; n < 4; n++) {
      const int c = n0 + wn * 64 + n * 16 + lr;
      if constexpr (MODE == 0) {
        if (c < 2048) {
#pragma unroll
          for (int ri = 0; ri < 4; ri++) {
            int rr = rb0 + ri;
            qkb[(size_t)(rr >> 10) * 2097152 + (size_t)(rr & 1023) * 2048 + c] =
                (f16)acc[m][n][ri];
          }
        } else {
          int bb = rb0 >> 10, nn = rb0 & 1023;
          f16x4 pk;
#pragma unroll
          for (int ri = 0; ri < 4; ri++) pk[ri] = (f16)acc[m][n][ri];
          *(f16x4*)(vTb + (size_t)bb * 1048576 + (size_t)(c - 2048) * 1024 + nn) = pk;
        }
      } else if constexpr (MODE == 1) {
        float* Cz = Cf + (size_t)z * sCb;
#pragma unroll
        for (int ri = 0; ri < 4; ri++)
          Cz[(size_t)(rb0 + ri) * N + c] = acc[m][n][ri] * 0.03125f; // SCALE_
      } else {
        float bv = bias[c];
#pragma unroll
        for (int ri = 0; ri < 4; ri++)
          Cf[(size_t)(rb0 + ri) * N + c] = acc[m][n][ri] + bv;
      }
    }
  }
}

// ---------- row softmax in-place on [rows][1024] f32 ----------
__global__ __launch_bounds__(256) void softmax_rows(float* __restrict__ p) {
  __shared__ float redm[4], reds[4];
  float* row = p + (size_t)blockIdx.x * 1024;
  const int t = threadIdx.x;
  float4 v = ((const float4*)row)[t];
  float mx = fmaxf(fmaxf(v.x, v.y), fmaxf(v.z, v.w));
#pragma unroll
  for (int d = 1; d < 64; d <<= 1) mx = fmaxf(mx, __shfl_xor(mx, d));
  if ((t & 63) == 0) redm[t >> 6] = mx;
  __syncthreads();
  mx = fmaxf(fmaxf(redm[0], redm[1]), fmaxf(redm[2], redm[3]));
  v.x = __expf(v.x - mx); v.y = __expf(v.y - mx);
  v.z = __expf(v.z - mx); v.w = __expf(v.w - mx);
  float s = v.x + v.y + v.z + v.w;
#pragma unroll
  for (int d = 1; d < 64; d <<= 1) s += __shfl_xor(s, d);
  if ((t & 63) == 0) reds[t >> 6] = s;
  __syncthreads();
  s = reds[0] + reds[1] + reds[2] + reds[3];
  float inv = 1.0f / s;
  v.x *= inv; v.y *= inv; v.z *= inv; v.w *= inv;
  ((float4*)row)[t] = v;
}

// ---------- flash MHA: 4 waves x 64 q-rows, KVBLK=64, dbuf K/V pipeline ----------
// grid (128, 4): x = b*16+h (so all 4 q-tiles of one (b,h) land on the SAME XCD
// under round-robin %8 dispatch -> K/V fetched once per XCD), y = q-tile.
__global__ __launch_bounds__(256, 2) void flash_kernel(
    const f16* __restrict__ qkb,   // [8][1024][2048] q|k
    const f16* __restrict__ vTb,   // [8][1024 d][1024 n]
    const unsigned char* __restrict__ mpad, // [8][1024]
    f16* __restrict__ ob) {        // [8192][1024]
  __shared__ __align__(16) f16 Ks[2][64 * 64];
  __shared__ __align__(16) f16 Vts[2][64 * 64];
  __shared__ __align__(16) f16 Ps[4][64 * 64];

  const int tid = threadIdx.x;
  const int w = tid >> 6, l = tid & 63;
  const int lr = l & 15, lg = l >> 4;
  const int bh = blockIdx.x, qt = blockIdx.y;
  const int h = bh & 15, b = bh >> 4;
  const int qbase = qt * 256 + w * 64;
  const f16* qk_b = qkb + (size_t)b * 2097152;
  const f16* vT_b = vTb + (size_t)b * 1048576 + (size_t)h * 64 * 1024;
  const unsigned char* mp = mpad + b * 1024;

  const int srow = l >> 3;            // 0..7 staging row within 8-row block
  const int schunk = (l & 7) ^ srow;  // pre-swizzled source chunk

  // stage tile t's K [64 tok][64 d] and V^T [64 d][64 tok] into buffer `buf`
  auto stage = [&](int buf, int t) {
#pragma unroll
    for (int i = 0; i < 2; i++) {
      int blk = w * 2 + i; // 8 rows each
      int row = blk * 8 + srow;
      gload16(qk_b + 1024 + (size_t)(t * 64 + row) * 2048 + h * 64 + schunk * 8,
              (void*)(Ks[buf] + blk * 512));
      gload16(vT_b + (size_t)row * 1024 + t * 64 + schunk * 8,
              (void*)(Vts[buf] + blk * 512));
    }
  };

  stage(0, 0); // prologue stage of tile 0

  // Q fragments (A-layout: row = lane&15, k = (lane>>4)*8 + j)
  f16x8 qf[4][2];
#pragma unroll
  for (int m = 0; m < 4; m++)
#pragma unroll
    for (int kk = 0; kk < 2; kk++) {
      int row = qbase + m * 16 + lr;
      int col = h * 64 + kk * 32 + lg * 8;
      qf[m][kk] = *(const f16x8*)(qk_b + (size_t)row * 2048 + col);
    }

  // row mask bits (bit m*4+ri)
  unsigned int mi_bits = 0;
#pragma unroll
  for (int m = 0; m < 4; m++)
#pragma unroll
    for (int ri = 0; ri < 4; ri++)
      mi_bits |= (mp[qbase + m * 16 + lg * 4 + ri] ? 1u : 0u) << (m * 4 + ri);

  const f32x4 zero4 = {0.f, 0.f, 0.f, 0.f};
  float mrun[4][4], lrun[4][4];
  f32x4 oacc[4][4];
#pragma unroll
  for (int m = 0; m < 4; m++)
#pragma unroll
    for (int i = 0; i < 4; i++) {
      mrun[m][i] = -3e38f; lrun[m][i] = 0.f; oacc[m][i] = zero4;
    }

  __syncthreads(); // drains prologue stage (implicit vmcnt(0)) + Q loads

  for (int t = 0; t < 16; t++) {
    const int cur = t & 1;
    if (t < 15) stage(cur ^ 1, t + 1); // prefetch next tile; latency hides under compute

    // S = Q K^T
    f32x4 sacc[4][4];
#pragma unroll
    for (int m = 0; m < 4; m++)
#pragma unroll
      for (int n = 0; n < 4; n++) sacc[m][n] = zero4;
#pragma unroll
    for (int kk = 0; kk < 2; kk++)
#pragma unroll
      for (int n = 0; n < 4; n++) {
        int krow = n * 16 + lr;
        int ch = (kk * 4 + lg) ^ (krow & 7);
        f16x8 kf = *(const f16x8*)&Ks[cur][krow * 64 + ch * 8];
#pragma unroll
        for (int m = 0; m < 4; m++)
          sacc[m][n] = __builtin_amdgcn_mfma_f32_16x16x32_f16(qf[m][kk], kf, sacc[m][n], 0, 0, 0);
      }

    unsigned int mj_bits = 0;
#pragma unroll
    for (int n = 0; n < 4; n++)
      mj_bits |= (mp[t * 64 + n * 16 + lr] ? 1u : 0u) << n;

    // online softmax + write P (swizzled per-wave LDS)
#pragma unroll
    for (int m = 0; m < 4; m++) {
#pragma unroll
      for (int ri = 0; ri < 4; ri++) {
        const bool rowok = (mi_bits >> (m * 4 + ri)) & 1;
        float sv[4];
        float vmax = -3e38f;
#pragma unroll
        for (int n = 0; n < 4; n++) {
          float s = sacc[m][n][ri];
          s = rowok ? (((mj_bits >> n) & 1) ? s * 0.125f : -1e30f) : 0.f;
          sv[n] = s;
          vmax = fmaxf(vmax, s);
        }
        vmax = rmax16(vmax);
        float nm = fmaxf(mrun[m][ri], vmax);
        float sc = __expf(mrun[m][ri] - nm); // 0 on first tile
        mrun[m][ri] = nm;
        float rs = 0.f;
        const int qr = m * 16 + lg * 4 + ri;
#pragma unroll
        for (int n = 0; n < 4; n++) {
          float pp = __expf(sv[n] - nm);
          rs += pp;
          int col = n * 16 + lr;
          Ps[w][qr * 64 + ((((col >> 3) ^ (qr & 7)) << 3)) + (col & 7)] = (f16)pp;
        }
        rs = rsum16(rs);
        lrun[m][ri] = lrun[m][ri] * sc + rs;
#pragma unroll
        for (int dn = 0; dn < 4; dn++) oacc[m][dn][ri] *= sc;
      }
    }
    asm volatile("s_waitcnt lgkmcnt(0)" ::: "memory");
    __builtin_amdgcn_sched_barrier(0);

    // O += P V   (A = P from Ps, B = rows of V^T from Vts)
#pragma unroll
    for (int kk = 0; kk < 2; kk++) {
      f16x8 pa[4];
#pragma unroll
      for (int m = 0; m < 4; m++) {
        int qr = m * 16 + lr;
        int ch = (kk * 4 + lg) ^ (qr & 7);
        pa[m] = *(const f16x8*)&Ps[w][qr * 64 + ch * 8];
      }
#pragma unroll
      for (int dn = 0; dn < 4; dn++) {
        int vrow = dn * 16 + lr;
        int ch = (kk * 4 + lg) ^ (vrow & 7);
        f16x8 vf = *(const f16x8*)&Vts[cur][vrow * 64 + ch * 8];
#pragma unroll
        for (int m = 0; m < 4; m++)
          oacc[m][dn] = __builtin_amdgcn_mfma_f32_16x16x32_f16(pa[m], vf, oacc[m][dn], 0, 0, 0);
      }
    }
    // single barrier per tile: implicit vmcnt(0) drains stage(t+1) AFTER a full
    // compute phase; lgkmcnt(0) retires all LDS reads of buf[cur] before any
    // wave's next-iter stage can overwrite buf[cur] (WAR-safe).
    __syncthreads();
  }

  // epilogue: O / l  -> ob f16
#pragma unroll
  for (int m = 0; m < 4; m++)
#pragma unroll
    for (int dn = 0; dn < 4; dn++)
#pragma unroll
      for (int ri = 0; ri < 4; ri++) {
        int qg = qbase + m * 16 + lg * 4 + ri;
        float o = oacc[m][dn][ri] / lrun[m][ri];
        ob[(size_t)(b * 1024 + qg) * 1024 + h * 64 + dn * 16 + lr] = (f16)o;
      }
}

// ---------- host ----------
extern "C" void kernel_launch(void* const* d_in, const int* in_sizes, int n_in,
                              void* d_out, int out_size, void* d_ws, size_t ws_size,
                              hipStream_t stream) {
  const float* x     = (const float*)d_in[0];
  const void*  mask  = d_in[1];
  const float* w_qkv = (const float*)d_in[2];
  const float* w_out = (const float*)d_in[3];
  const float* b_out = (const float*)d_in[4];
  float* out  = (float*)d_out;           // [8192][1024]
  float* attn = out + 8388608;           // [8][1024][1024]

  char* ws = (char*)d_ws;
  f16* xb    = (f16*)(ws);                    // [8192][1024]          16.78 MB (dead after gemm<0>)
  f16* wqkvT = (f16*)(ws + 16777216);         // [3072][1024]           6.29 MB
  f16* woutT = (f16*)(ws + 23068672);         // [1024][1024]           2.10 MB
  f16* qkb   = (f16*)(ws + 25165824);         // [8][1024][2048]       33.55 MB
  f16* vTb   = (f16*)(ws + 58720256);         // [8][1024 d][1024 n]   16.78 MB
  f16* ob    = xb;                            // aliases xb (lifetimes disjoint)
  unsigned char* mpad = (unsigned char*)(ws + 75497472); // [8][1024]

  cast_f16<<<8192, 256, 0, stream>>>(x, xb, 2097152);
  transpose_cast<<<dim3(48, 16), 256, 0, stream>>>(w_qkv, wqkvT, 1024, 3072);
  transpose_cast<<<dim3(16, 16), 256, 0, stream>>>(w_out, woutT, 1024, 1024);
  prep_mask<<<32, 256, 0, stream>>>(mask, mpad);

  // qkv = x @ w_qkv  (M=8192, N=3072, K=1024)
  gemm_nt<0><<<dim3(24, 64), 256, 0, stream>>>(xb, 1024, 0, wqkvT, 1024, 0,
                                               nullptr, 0, nullptr, qkb, vTb, 3072, 1024);
  // pooled S = q_ k_^T * SCALE_  (per batch, M=N=K=1024)
  gemm_nt<1><<<dim3(8, 8, 8), 256, 0, stream>>>(qkb, 2048, 2097152, qkb + 1024, 2048, 2097152,
                                                attn, 1048576, nullptr, nullptr, nullptr, 1024, 1024);
  softmax_rows<<<8192, 256, 0, stream>>>(attn);

  flash_kernel<<<dim3(128, 4), 256, 0, stream>>>(qkb, vTb, mpad, ob);

  // out = ob @ w_out + b_out  (M=8192, N=1024, K=1024)
  gemm_nt<2><<<dim3(8, 64), 256, 0, stream>>>(ob, 1024, 0, woutT, 1024, 0,
                                              out, 0, b_out, nullptr, nullptr, 1024, 1024);
}

// Round 7
// 338.203 us; speedup vs baseline: 1.6677x; 1.4868x over previous
//
#include <hip/hip_runtime.h>

typedef _Float16 f16;
typedef _Float16 f16x8 __attribute__((ext_vector_type(8)));
typedef _Float16 f16x4 __attribute__((ext_vector_type(4)));
typedef float    f32x4 __attribute__((ext_vector_type(4)));

#define DEV __device__ __forceinline__

// ---------- helpers ----------
DEV void gload16(const void* g, void* l) {
  __builtin_amdgcn_global_load_lds(
      (const __attribute__((address_space(1))) unsigned int*)g,
      (__attribute__((address_space(3))) unsigned int*)l, 16, 0, 0);
}

// ---------- elementwise f32 -> f16 cast ----------
__global__ void cast_f16(const float* __restrict__ s, f16* __restrict__ d, int n4) {
  int i = blockIdx.x * blockDim.x + threadIdx.x;
  if (i < n4) {
    float4 v = ((const float4*)s)[i];
    f16x4 o;
    o[0] = (f16)v.x; o[1] = (f16)v.y; o[2] = (f16)v.z; o[3] = (f16)v.w;
    ((f16x4*)d)[i] = o;
  }
}

// ---------- transpose + cast: src[R][C] f32 -> dst[C][R] f16 ----------
__global__ void transpose_cast(const float* __restrict__ src, f16* __restrict__ dst,
                               int R, int C) {
  __shared__ float tile[64][65];
  const int cb = blockIdx.x * 64, rb = blockIdx.y * 64;
  const int tx = threadIdx.x & 63, ty = threadIdx.x >> 6; // ty 0..3
#pragma unroll
  for (int i = 0; i < 64; i += 4)
    tile[ty + i][tx] = src[(size_t)(rb + ty + i) * C + cb + tx];
  __syncthreads();
#pragma unroll
  for (int i = 0; i < 64; i += 4)
    dst[(size_t)(cb + ty + i) * R + rb + tx] = (f16)tile[tx][ty + i];
}

// ---------- mask prep: build mpad[8][1024] u8 with CLS=1, format auto-detect ----------
__global__ void prep_mask(const void* __restrict__ mask, unsigned char* __restrict__ mpad) {
  int i = blockIdx.x * blockDim.x + threadIdx.x; // 0..8191
  if (i >= 8192) return;
  const unsigned int* wv = (const unsigned int*)mask;
  bool anyf32 = false, anybig = false;
  for (int k = 0; k < 64; k++) {
    unsigned int x = wv[k];
    if (x == 0x3f800000u) anyf32 = true;
    else if (x > 1u) anybig = true;
  }
  int b = i >> 10, j = i & 1023;
  bool v;
  if (j == 0) v = true;
  else {
    size_t idx = (size_t)b * 1023 + (j - 1);
    if (anyf32)      v = ((const float*)mask)[idx] != 0.f;
    else if (anybig) v = ((const unsigned char*)mask)[idx] != 0;
    else             v = ((const int*)mask)[idx] != 0;
  }
  mpad[i] = v ? 1 : 0;
}

// ---------- generic 128x128 f16 MFMA GEMM: C = A[M,K] * Bt[N,K]^T ----------
// MODE 0: qkv — cols<2048 -> qkb[b][n][2048]; cols>=2048 -> vTb[b][d][n] (transposed)
// MODE 1: pooled S — f32 * SCALE_ -> Cf (+z*sCb)
// MODE 2: out proj — f32 + bias -> Cf
template <int MODE>
__global__ __launch_bounds__(256, 2) void gemm_nt(
    const f16* __restrict__ A, int lda, long sAb,
    const f16* __restrict__ Bt, int ldb, long sBb,
    float* __restrict__ Cf, long sCb,
    const float* __restrict__ bias,
    f16* __restrict__ qkb, f16* __restrict__ vTb,
    int N, int K) {
  __shared__ __align__(16) f16 As[128 * 32];
  __shared__ __align__(16) f16 Bs[128 * 32];
  const int tid = threadIdx.x;
  const int w = tid >> 6, l = tid & 63;
  const int lr = l & 15, lg = l >> 4;
  const int wm = w >> 1, wn = w & 1;
  const int m0 = blockIdx.y * 128, n0 = blockIdx.x * 128;
  const int z = blockIdx.z;
  const f16* Ab = A + (size_t)z * sAb;
  const f16* Btb = Bt + (size_t)z * sBb;

  const f32x4 zero4 = {0.f, 0.f, 0.f, 0.f};
  f32x4 acc[4][4];
#pragma unroll
  for (int m = 0; m < 4; m++)
#pragma unroll
    for (int n = 0; n < 4; n++) acc[m][n] = zero4;

  const int srow = l >> 2;               // row within 16-row staging block
  const int sch = (l & 3) ^ (srow & 3);  // pre-swizzled source chunk (involution)

  for (int k0 = 0; k0 < K; k0 += 32) {
#pragma unroll
    for (int i = 0; i < 2; i++) {
      int blk = w * 2 + i; // 0..7, 16 rows each
      int row = blk * 16 + srow;
      gload16(Ab + (size_t)(m0 + row) * lda + k0 + sch * 8, (void*)(As + blk * 512));
      gload16(Btb + (size_t)(n0 + row) * ldb + k0 + sch * 8, (void*)(Bs + blk * 512));
    }
    __syncthreads();
    f16x8 af[4], bf[4];
#pragma unroll
    for (int m = 0; m < 4; m++) {
      int row = wm * 64 + m * 16 + lr;
      af[m] = *(const f16x8*)&As[row * 32 + ((lg ^ (row & 3)) << 3)];
    }
#pragma unroll
    for (int n = 0; n < 4; n++) {
      int row = wn * 64 + n * 16 + lr;
      bf[n] = *(const f16x8*)&Bs[row * 32 + ((lg ^ (row & 3)) << 3)];
    }
#pragma unroll
    for (int m = 0; m < 4; m++)
#pragma unroll
      for (int n = 0; n < 4; n++)
        acc[m][n] = __builtin_amdgcn_mfma_f32_16x16x32_f16(af[m], bf[n], acc[m][n], 0, 0, 0);
    __syncthreads();
  }

  // epilogue: C layout col = lane&15, row = (lane>>4)*4 + reg
#pragma unroll
  for (int m = 0; m < 4; m++) {
    const int rb0 = m0 + wm * 64 + m * 16 + lg * 4;
#pragma unroll
    for (int n = 0; n < 4; n++) {
      const int c = n0 + wn * 64 + n * 16 + lr;
      if constexpr (MODE == 0) {
        if (c < 2048) {
#pragma unroll
          for (int ri = 0; ri < 4; ri++) {
            int rr = rb0 + ri;
            qkb[(size_t)(rr >> 10) * 2097152 + (size_t)(rr & 1023) * 2048 + c] =
                (f16)acc[m][n][ri];
          }
        } else {
          int bb = rb0 >> 10, nn = rb0 & 1023;
          f16x4 pk;
#pragma unroll
          for (int ri = 0; ri < 4; ri++) pk[ri] = (f16)acc[m][n][ri];
          *(f16x4*)(vTb + (size_t)bb * 1048576 + (size_t)(c - 2048) * 1024 + nn) = pk;
        }
      } else if constexpr (MODE == 1) {
        float* Cz = Cf + (size_t)z * sCb;
#pragma unroll
        for (int ri = 0; ri < 4; ri++)
          Cz[(size_t)(rb0 + ri) * N + c] = acc[m][n][ri] * 0.03125f; // SCALE_
      } else {
        float bv = bias[c];
#pragma unroll
        for (int ri = 0; ri < 4; ri++)
          Cf[(size_t)(rb0 + ri) * N + c] = acc[m][n][ri] + bv;
      }
    }
  }
}

// ---------- row softmax in-place on [rows][1024] f32 ----------
__global__ __launch_bounds__(256) void softmax_rows(float* __restrict__ p) {
  __shared__ float redm[4], reds[4];
  float* row = p + (size_t)blockIdx.x * 1024;
  const int t = threadIdx.x;
  float4 v = ((const float4*)row)[t];
  float mx = fmaxf(fmaxf(v.x, v.y), fmaxf(v.z, v.w));
#pragma unroll
  for (int d = 1; d < 64; d <<= 1) mx = fmaxf(mx, __shfl_xor(mx, d));
  if ((t & 63) == 0) redm[t >> 6] = mx;
  __syncthreads();
  mx = fmaxf(fmaxf(redm[0], redm[1]), fmaxf(redm[2], redm[3]));
  v.x = __expf(v.x - mx); v.y = __expf(v.y - mx);
  v.z = __expf(v.z - mx); v.w = __expf(v.w - mx);
  float s = v.x + v.y + v.z + v.w;
#pragma unroll
  for (int d = 1; d < 64; d <<= 1) s += __shfl_xor(s, d);
  if ((t & 63) == 0) reds[t >> 6] = s;
  __syncthreads();
  s = reds[0] + reds[1] + reds[2] + reds[3];
  float inv = 1.0f / s;
  v.x *= inv; v.y *= inv; v.z *= inv; v.w *= inv;
  ((float4*)row)[t] = v;
}

// ---------- flash MHA: swapped QK^T -> lane-local softmax rows ----------
// grid (128, 4): x = b*16+h (4 q-tiles of one (b,h) share an XCD), y = q-tile.
__global__ __launch_bounds__(256, 2) void flash_kernel(
    const f16* __restrict__ qkb,   // [8][1024][2048] q|k
    const f16* __restrict__ vTb,   // [8][1024 d][1024 n]
    const unsigned char* __restrict__ mpad, // [8][1024]
    f16* __restrict__ ob) {        // [8192][1024]
  __shared__ __align__(16) f16 Ks[2][64 * 64];
  __shared__ __align__(16) f16 Vts[2][64 * 64];
  __shared__ __align__(16) f16 Ps[4][64 * 64];

  const int tid = threadIdx.x;
  const int w = tid >> 6, l = tid & 63;
  const int lr = l & 15, lg = l >> 4;
  const int bh = blockIdx.x, qt = blockIdx.y;
  const int h = bh & 15, b = bh >> 4;
  const int qbase = qt * 256 + w * 64;
  const f16* qk_b = qkb + (size_t)b * 2097152;
  const f16* vT_b = vTb + (size_t)b * 1048576 + (size_t)h * 64 * 1024;
  const unsigned char* mp = mpad + b * 1024;

  const int srow = l >> 3;            // 0..7 staging row within 8-row block
  const int schunk = (l & 7) ^ srow;  // pre-swizzled source chunk

  auto stage = [&](int buf, int t) {
#pragma unroll
    for (int i = 0; i < 2; i++) {
      int blk = w * 2 + i; // 8 rows each
      int row = blk * 8 + srow;
      gload16(qk_b + 1024 + (size_t)(t * 64 + row) * 2048 + h * 64 + schunk * 8,
              (void*)(Ks[buf] + blk * 512));
      gload16(vT_b + (size_t)row * 1024 + t * 64 + schunk * 8,
              (void*)(Vts[buf] + blk * 512));
    }
  };

  stage(0, 0); // prologue stage of tile 0

  // Q fragments (row = lane&15 -> used as MFMA *second* operand, so qrow -> C col)
  f16x8 qf[4][2];
#pragma unroll
  for (int m = 0; m < 4; m++)
#pragma unroll
    for (int kk = 0; kk < 2; kk++) {
      int row = qbase + m * 16 + lr;
      int col = h * 64 + kk * 32 + lg * 8;
      qf[m][kk] = *(const f16x8*)(qk_b + (size_t)row * 2048 + col);
    }

  // per-lane q-row mask bits: bit m = mask of row qbase + m*16 + lr
  unsigned int mi4 = 0;
#pragma unroll
  for (int m = 0; m < 4; m++)
    mi4 |= (mp[qbase + m * 16 + lr] ? 1u : 0u) << m;

  const f32x4 zero4 = {0.f, 0.f, 0.f, 0.f};
  float mrun[4], lrun[4];   // per-lane state of row (m*16+lr)
  f32x4 oacc[4][4];
#pragma unroll
  for (int m = 0; m < 4; m++) {
    mrun[m] = -3e38f; lrun[m] = 0.f;
#pragma unroll
    for (int i = 0; i < 4; i++) oacc[m][i] = zero4;
  }

  __syncthreads(); // drains prologue stage (implicit vmcnt(0)) + Q loads

  for (int t = 0; t < 16; t++) {
    const int cur = t & 1;
    if (t < 15) stage(cur ^ 1, t + 1); // prefetch; latency hides under compute

    // S^T = K Q^T : st[n][m][ri] = S[qrow = m*16+lr][ktok = n*16+lg*4+ri]
    f32x4 st[4][4];
#pragma unroll
    for (int n = 0; n < 4; n++)
#pragma unroll
      for (int m = 0; m < 4; m++) st[n][m] = zero4;
#pragma unroll
    for (int kk = 0; kk < 2; kk++)
#pragma unroll
      for (int n = 0; n < 4; n++) {
        int krow = n * 16 + lr;
        int ch = (kk * 4 + lg) ^ (krow & 7);
        f16x8 kf = *(const f16x8*)&Ks[cur][krow * 64 + ch * 8];
#pragma unroll
        for (int m = 0; m < 4; m++)
          st[n][m] = __builtin_amdgcn_mfma_f32_16x16x32_f16(kf, qf[m][kk], st[n][m], 0, 0, 0);
      }

    // ktok-mask words: byte ri of mw[n] = mask[t*64 + n*16 + lg*4 + ri]
    unsigned int mw[4];
#pragma unroll
    for (int n = 0; n < 4; n++)
      mw[n] = *(const unsigned int*)(mp + t * 64 + n * 16 + lg * 4);

    // lane-local online softmax: each lane owns row (m*16+lr); 4 lg-copies merged
    // by 2 shuffles (xor 16, 32).
#pragma unroll
    for (int m = 0; m < 4; m++) {
      const bool rowok = (mi4 >> m) & 1;
      float sv[4][4];
      float vmax = -3e38f;
#pragma unroll
      for (int n = 0; n < 4; n++)
#pragma unroll
        for (int ri = 0; ri < 4; ri++) {
          float s = st[n][m][ri];
          bool ok = ((mw[n] >> (8 * ri)) & 255u) != 0u;
          s = rowok ? (ok ? s * 0.125f : -1e30f) : 0.f;
          sv[n][ri] = s;
          vmax = fmaxf(vmax, s);
        }
      vmax = fmaxf(vmax, __shfl_xor(vmax, 16));
      vmax = fmaxf(vmax, __shfl_xor(vmax, 32));
      float nm_ = fmaxf(mrun[m], vmax);
      float sc = __expf(mrun[m] - nm_); // 0 on first tile
      mrun[m] = nm_;
      float rs = 0.f;
      const int qr = m * 16 + lr;
#pragma unroll
      for (int n = 0; n < 4; n++) {
        f16x4 pk;
#pragma unroll
        for (int ri = 0; ri < 4; ri++) {
          float pp = __expf(sv[n][ri] - nm_);
          rs += pp;
          pk[ri] = (f16)pp;
        }
        const int col0 = n * 16 + lg * 4;
        const int swz = (col0 >> 3) ^ (qr & 7);
        *(f16x4*)&Ps[w][qr * 64 + swz * 8 + (col0 & 7)] = pk; // b64 write, 4 ktok
      }
      rs += __shfl_xor(rs, 16);
      rs += __shfl_xor(rs, 32);
      lrun[m] = lrun[m] * sc + rs;
      // oacc row (m*16+lg*4+ri) is owned by lane (lg*4+ri): broadcast its sc
      float scb[4];
#pragma unroll
      for (int ri = 0; ri < 4; ri++) scb[ri] = __shfl(sc, lg * 4 + ri);
#pragma unroll
      for (int dn = 0; dn < 4; dn++)
#pragma unroll
        for (int ri = 0; ri < 4; ri++) oacc[m][dn][ri] *= scb[ri];
    }
    asm volatile("s_waitcnt lgkmcnt(0)" ::: "memory");
    __builtin_amdgcn_sched_barrier(0);

    // O += P V   (A = P from Ps, B = rows of V^T from Vts)
#pragma unroll
    for (int kk = 0; kk < 2; kk++) {
      f16x8 pa[4];
#pragma unroll
      for (int m = 0; m < 4; m++) {
        int qr = m * 16 + lr;
        int ch = (kk * 4 + lg) ^ (qr & 7);
        pa[m] = *(const f16x8*)&Ps[w][qr * 64 + ch * 8];
      }
#pragma unroll
      for (int dn = 0; dn < 4; dn++) {
        int vrow = dn * 16 + lr;
        int ch = (kk * 4 + lg) ^ (vrow & 7);
        f16x8 vf = *(const f16x8*)&Vts[cur][vrow * 64 + ch * 8];
#pragma unroll
        for (int m = 0; m < 4; m++)
          oacc[m][dn] = __builtin_amdgcn_mfma_f32_16x16x32_f16(pa[m], vf, oacc[m][dn], 0, 0, 0);
      }
    }
    // single barrier per tile: implicit vmcnt(0) drains stage(t+1) AFTER a full
    // compute phase; lgkmcnt(0) retires LDS reads of buf[cur] (WAR-safe).
    __syncthreads();
  }

  // epilogue: O / l -> ob f16 (broadcast lrun from owner lane lg*4+ri)
#pragma unroll
  for (int m = 0; m < 4; m++) {
    float lb[4];
#pragma unroll
    for (int ri = 0; ri < 4; ri++) lb[ri] = __shfl(lrun[m], lg * 4 + ri);
#pragma unroll
    for (int dn = 0; dn < 4; dn++)
#pragma unroll
      for (int ri = 0; ri < 4; ri++) {
        int qg = qbase + m * 16 + lg * 4 + ri;
        float o = oacc[m][dn][ri] / lb[ri];
        ob[(size_t)(b * 1024 + qg) * 1024 + h * 64 + dn * 16 + lr] = (f16)o;
      }
  }
}

// ---------- host ----------
extern "C" void kernel_launch(void* const* d_in, const int* in_sizes, int n_in,
                              void* d_out, int out_size, void* d_ws, size_t ws_size,
                              hipStream_t stream) {
  const float* x     = (const float*)d_in[0];
  const void*  mask  = d_in[1];
  const float* w_qkv = (const float*)d_in[2];
  const float* w_out = (const float*)d_in[3];
  const float* b_out = (const float*)d_in[4];
  float* out  = (float*)d_out;           // [8192][1024]
  float* attn = out + 8388608;           // [8][1024][1024]

  char* ws = (char*)d_ws;
  f16* xb    = (f16*)(ws);                    // [8192][1024]          16.78 MB (dead after gemm<0>)
  f16* wqkvT = (f16*)(ws + 16777216);         // [3072][1024]           6.29 MB
  f16* woutT = (f16*)(ws + 23068672);         // [1024][1024]           2.10 MB
  f16* qkb   = (f16*)(ws + 25165824);         // [8][1024][2048]       33.55 MB
  f16* vTb   = (f16*)(ws + 58720256);         // [8][1024 d][1024 n]   16.78 MB
  f16* ob    = xb;                            // aliases xb (lifetimes disjoint)
  unsigned char* mpad = (unsigned char*)(ws + 75497472); // [8][1024]

  cast_f16<<<8192, 256, 0, stream>>>(x, xb, 2097152);
  transpose_cast<<<dim3(48, 16), 256, 0, stream>>>(w_qkv, wqkvT, 1024, 3072);
  transpose_cast<<<dim3(16, 16), 256, 0, stream>>>(w_out, woutT, 1024, 1024);
  prep_mask<<<32, 256, 0, stream>>>(mask, mpad);

  // qkv = x @ w_qkv  (M=8192, N=3072, K=1024)
  gemm_nt<0><<<dim3(24, 64), 256, 0, stream>>>(xb, 1024, 0, wqkvT, 1024, 0,
                                               nullptr, 0, nullptr, qkb, vTb, 3072, 1024);
  // pooled S = q_ k_^T * SCALE_  (per batch, M=N=K=1024)
  gemm_nt<1><<<dim3(8, 8, 8), 256, 0, stream>>>(qkb, 2048, 2097152, qkb + 1024, 2048, 2097152,
                                                attn, 1048576, nullptr, nullptr, nullptr, 1024, 1024);
  softmax_rows<<<8192, 256, 0, stream>>>(attn);

  flash_kernel<<<dim3(128, 4), 256, 0, stream>>>(qkb, vTb, mpad, ob);

  // out = ob @ w_out + b_out  (M=8192, N=1024, K=1024)
  gemm_nt<2><<<dim3(8, 64), 256, 0, stream>>>(ob, 1024, 0, woutT, 1024, 0,
                                              out, 0, b_out, nullptr, nullptr, 1024, 1024);
}

// Round 8
// 301.555 us; speedup vs baseline: 1.8704x; 1.1215x over previous
//
#include <hip/hip_runtime.h>

typedef _Float16 f16;
typedef _Float16 f16x8 __attribute__((ext_vector_type(8)));
typedef _Float16 f16x4 __attribute__((ext_vector_type(4)));
typedef float    f32x4 __attribute__((ext_vector_type(4)));

#define DEV __device__ __forceinline__

// ---------- helpers ----------
DEV void gload16(const void* g, void* l) {
  __builtin_amdgcn_global_load_lds(
      (const __attribute__((address_space(1))) unsigned int*)g,
      (__attribute__((address_space(3))) unsigned int*)l, 16, 0, 0);
}

// ---------- elementwise f32 -> f16 cast ----------
__global__ void cast_f16(const float* __restrict__ s, f16* __restrict__ d, int n4) {
  int i = blockIdx.x * blockDim.x + threadIdx.x;
  if (i < n4) {
    float4 v = ((const float4*)s)[i];
    f16x4 o;
    o[0] = (f16)v.x; o[1] = (f16)v.y; o[2] = (f16)v.z; o[3] = (f16)v.w;
    ((f16x4*)d)[i] = o;
  }
}

// ---------- transpose + cast: src[R][C] f32 -> dst[C][R] f16 ----------
__global__ void transpose_cast(const float* __restrict__ src, f16* __restrict__ dst,
                               int R, int C) {
  __shared__ float tile[64][65];
  const int cb = blockIdx.x * 64, rb = blockIdx.y * 64;
  const int tx = threadIdx.x & 63, ty = threadIdx.x >> 6; // ty 0..3
#pragma unroll
  for (int i = 0; i < 64; i += 4)
    tile[ty + i][tx] = src[(size_t)(rb + ty + i) * C + cb + tx];
  __syncthreads();
#pragma unroll
  for (int i = 0; i < 64; i += 4)
    dst[(size_t)(cb + ty + i) * R + rb + tx] = (f16)tile[tx][ty + i];
}

// ---------- mask prep: build mpad[8][1024] u8 with CLS=1, format auto-detect ----------
__global__ void prep_mask(const void* __restrict__ mask, unsigned char* __restrict__ mpad) {
  int i = blockIdx.x * blockDim.x + threadIdx.x; // 0..8191
  if (i >= 8192) return;
  const unsigned int* wv = (const unsigned int*)mask;
  bool anyf32 = false, anybig = false;
  for (int k = 0; k < 64; k++) {
    unsigned int x = wv[k];
    if (x == 0x3f800000u) anyf32 = true;
    else if (x > 1u) anybig = true;
  }
  int b = i >> 10, j = i & 1023;
  bool v;
  if (j == 0) v = true;
  else {
    size_t idx = (size_t)b * 1023 + (j - 1);
    if (anyf32)      v = ((const float*)mask)[idx] != 0.f;
    else if (anybig) v = ((const unsigned char*)mask)[idx] != 0;
    else             v = ((const int*)mask)[idx] != 0;
  }
  mpad[i] = v ? 1 : 0;
}

// ---------- 8-wave 256x128 8-phase-style GEMM, K=1024 fixed ----------
// C = A[M,1024] * Bt[N,1024]^T.  BK=64, 16 K-tiles, 2 phases/tile, 16 MFMA/phase.
// LDS 96KB: 2 bufs x (A 256x64 + B 128x64) f16.  Counted vmcnt(3), raw barriers.
// MODE 0: qkv scatter (c<2048 -> qkb[b][n][2048]; else vTb[b][d][n])
// MODE 1: f32 * SCALE_ -> Cf (+z*sCb)    MODE 2: f32 + bias -> Cf
template <int MODE>
__global__ __launch_bounds__(512, 1) void gemm8(
    const f16* __restrict__ A, int lda, long sAb,
    const f16* __restrict__ Bt, int ldb, long sBb,
    float* __restrict__ Cf, long sCb,
    const float* __restrict__ bias,
    f16* __restrict__ qkb, f16* __restrict__ vTb, int N) {
  __shared__ __align__(16) f16 smem[2 * 24576]; // per buf: A @0 (16384), B @16384 (8192)
  const int tid = threadIdx.x;
  const int w = tid >> 6, l = tid & 63;
  const int lr = l & 15, lg = l >> 4;
  const int wm = w >> 1, wn = w & 1;           // wave tile: rows wm*64, cols wn*64
  const int m0 = blockIdx.y * 256, n0 = blockIdx.x * 128;
  const int z = blockIdx.z;
  const f16* Ab = A + (size_t)z * sAb;
  const f16* Btb = Bt + (size_t)z * sBb;

  const int gr = w * 8 + (l >> 3);             // staging row within 64-row group
  const int gsch = (l & 7) ^ (l >> 3);         // pre-swizzled global chunk (involution)

  // stage one 8KB round: A round r in 0..3 (rows r*64..r*64+63), B round r in 0..1
  auto stageA = [&](int buf, int kt, int r) {
    gload16(Ab + (size_t)(m0 + r * 64 + gr) * lda + kt * 64 + gsch * 8,
            (void*)(smem + buf * 24576 + r * 4096 + w * 512));
  };
  auto stageB = [&](int buf, int kt, int r) {
    gload16(Btb + (size_t)(n0 + r * 64 + gr) * ldb + kt * 64 + gsch * 8,
            (void*)(smem + buf * 24576 + 16384 + r * 4096 + w * 512));
  };

  // prologue: stage tile 0 -> buf 0 (6 loads/wave)
  stageA(0, 0, 0); stageA(0, 0, 1); stageA(0, 0, 2); stageA(0, 0, 3);
  stageB(0, 0, 0); stageB(0, 0, 1);

  const f32x4 zero4 = {0.f, 0.f, 0.f, 0.f};
  f32x4 acc[4][4];
#pragma unroll
  for (int m = 0; m < 4; m++)
#pragma unroll
    for (int n = 0; n < 4; n++) acc[m][n] = zero4;

  for (int T = 0; T < 16; ++T) {
    const int cur = T & 1, nxt = cur ^ 1;
    const f16* pA = smem + cur * 24576;
    const f16* pB = pA + 16384;

    // ---- phase A: stage(3) -> vmcnt -> barrier -> reads(bf,af01) -> MFMA m0,1 ----
    if (T < 15) {
      stageA(nxt, T + 1, 0); stageA(nxt, T + 1, 1); stageA(nxt, T + 1, 2);
      asm volatile("s_waitcnt vmcnt(3)" ::: "memory"); // tile T's 6 loads landed
    } else {
      asm volatile("s_waitcnt vmcnt(0)" ::: "memory");
    }
    __builtin_amdgcn_s_barrier();

    f16x8 bf[4][2], af[2][2];
#pragma unroll
    for (int n = 0; n < 4; n++)
#pragma unroll
      for (int kk = 0; kk < 2; kk++) {
        int row = wn * 64 + n * 16 + lr;
        bf[n][kk] = *(const f16x8*)&pB[row * 64 + (((kk * 4 + lg) ^ (row & 7)) << 3)];
      }
#pragma unroll
    for (int mi = 0; mi < 2; mi++)
#pragma unroll
      for (int kk = 0; kk < 2; kk++) {
        int row = wm * 64 + mi * 16 + lr;
        af[mi][kk] = *(const f16x8*)&pA[row * 64 + (((kk * 4 + lg) ^ (row & 7)) << 3)];
      }
    asm volatile("s_waitcnt lgkmcnt(0)" ::: "memory");
    __builtin_amdgcn_sched_barrier(0);
    __builtin_amdgcn_s_setprio(1);
#pragma unroll
    for (int mi = 0; mi < 2; mi++)
#pragma unroll
      for (int n = 0; n < 4; n++)
#pragma unroll
        for (int kk = 0; kk < 2; kk++)
          acc[mi][n] = __builtin_amdgcn_mfma_f32_16x16x32_f16(af[mi][kk], bf[n][kk], acc[mi][n], 0, 0, 0);
    __builtin_amdgcn_s_setprio(0);
    __builtin_amdgcn_sched_barrier(0);
    __builtin_amdgcn_s_barrier();

    // ---- phase B: reads(af23) + stage(3) -> barrier -> MFMA m2,3 ----
    f16x8 af2[2][2];
#pragma unroll
    for (int mi = 0; mi < 2; mi++)
#pragma unroll
      for (int kk = 0; kk < 2; kk++) {
        int row = wm * 64 + (2 + mi) * 16 + lr;
        af2[mi][kk] = *(const f16x8*)&pA[row * 64 + (((kk * 4 + lg) ^ (row & 7)) << 3)];
      }
    if (T < 15) {
      stageA(nxt, T + 1, 3); stageB(nxt, T + 1, 0); stageB(nxt, T + 1, 1);
    }
    __builtin_amdgcn_s_barrier();
    asm volatile("s_waitcnt lgkmcnt(0)" ::: "memory");
    __builtin_amdgcn_sched_barrier(0);
    __builtin_amdgcn_s_setprio(1);
#pragma unroll
    for (int mi = 0; mi < 2; mi++)
#pragma unroll
      for (int n = 0; n < 4; n++)
#pragma unroll
        for (int kk = 0; kk < 2; kk++)
          acc[2 + mi][n] = __builtin_amdgcn_mfma_f32_16x16x32_f16(af2[mi][kk], bf[n][kk], acc[2 + mi][n], 0, 0, 0);
    __builtin_amdgcn_s_setprio(0);
    __builtin_amdgcn_sched_barrier(0);
    __builtin_amdgcn_s_barrier();
  }

  // epilogue: C layout col = lane&15, row = (lane>>4)*4 + reg
#pragma unroll
  for (int m = 0; m < 4; m++) {
    const int rb0 = m0 + wm * 64 + m * 16 + lg * 4;
#pragma unroll
    for (int n = 0; n < 4; n++) {
      const int c = n0 + wn * 64 + n * 16 + lr;
      if constexpr (MODE == 0) {
        if (c < 2048) {
#pragma unroll
          for (int ri = 0; ri < 4; ri++) {
            int rr = rb0 + ri;
            qkb[(size_t)(rr >> 10) * 2097152 + (size_t)(rr & 1023) * 2048 + c] =
                (f16)acc[m][n][ri];
          }
        } else {
          int bb = rb0 >> 10, nn = rb0 & 1023;
          f16x4 pk;
#pragma unroll
          for (int ri = 0; ri < 4; ri++) pk[ri] = (f16)acc[m][n][ri];
          *(f16x4*)(vTb + (size_t)bb * 1048576 + (size_t)(c - 2048) * 1024 + nn) = pk;
        }
      } else if constexpr (MODE == 1) {
        float* Cz = Cf + (size_t)z * sCb;
#pragma unroll
        for (int ri = 0; ri < 4; ri++)
          Cz[(size_t)(rb0 + ri) * N + c] = acc[m][n][ri] * 0.03125f; // SCALE_
      } else {
        float bv = bias[c];
#pragma unroll
        for (int ri = 0; ri < 4; ri++)
          Cf[(size_t)(rb0 + ri) * N + c] = acc[m][n][ri] + bv;
      }
    }
  }
}

// ---------- row softmax in-place on [rows][1024] f32 ----------
__global__ __launch_bounds__(256) void softmax_rows(float* __restrict__ p) {
  __shared__ float redm[4], reds[4];
  float* row = p + (size_t)blockIdx.x * 1024;
  const int t = threadIdx.x;
  float4 v = ((const float4*)row)[t];
  float mx = fmaxf(fmaxf(v.x, v.y), fmaxf(v.z, v.w));
#pragma unroll
  for (int d = 1; d < 64; d <<= 1) mx = fmaxf(mx, __shfl_xor(mx, d));
  if ((t & 63) == 0) redm[t >> 6] = mx;
  __syncthreads();
  mx = fmaxf(fmaxf(redm[0], redm[1]), fmaxf(redm[2], redm[3]));
  v.x = __expf(v.x - mx); v.y = __expf(v.y - mx);
  v.z = __expf(v.z - mx); v.w = __expf(v.w - mx);
  float s = v.x + v.y + v.z + v.w;
#pragma unroll
  for (int d = 1; d < 64; d <<= 1) s += __shfl_xor(s, d);
  if ((t & 63) == 0) reds[t >> 6] = s;
  __syncthreads();
  s = reds[0] + reds[1] + reds[2] + reds[3];
  float inv = 1.0f / s;
  v.x *= inv; v.y *= inv; v.z *= inv; v.w *= inv;
  ((float4*)row)[t] = v;
}

// ---------- flash MHA: swapped QK^T -> lane-local softmax rows ----------
// grid (128, 4): x = b*16+h (4 q-tiles of one (b,h) share an XCD), y = q-tile.
__global__ __launch_bounds__(256, 2) void flash_kernel(
    const f16* __restrict__ qkb,   // [8][1024][2048] q|k
    const f16* __restrict__ vTb,   // [8][1024 d][1024 n]
    const unsigned char* __restrict__ mpad, // [8][1024]
    f16* __restrict__ ob) {        // [8192][1024]
  __shared__ __align__(16) f16 Ks[2][64 * 64];
  __shared__ __align__(16) f16 Vts[2][64 * 64];
  __shared__ __align__(16) f16 Ps[4][64 * 64];

  const int tid = threadIdx.x;
  const int w = tid >> 6, l = tid & 63;
  const int lr = l & 15, lg = l >> 4;
  const int bh = blockIdx.x, qt = blockIdx.y;
  const int h = bh & 15, b = bh >> 4;
  const int qbase = qt * 256 + w * 64;
  const f16* qk_b = qkb + (size_t)b * 2097152;
  const f16* vT_b = vTb + (size_t)b * 1048576 + (size_t)h * 64 * 1024;
  const unsigned char* mp = mpad + b * 1024;

  const int srow = l >> 3;            // 0..7 staging row within 8-row block
  const int schunk = (l & 7) ^ srow;  // pre-swizzled source chunk

  auto stage = [&](int buf, int t) {
#pragma unroll
    for (int i = 0; i < 2; i++) {
      int blk = w * 2 + i; // 8 rows each
      int row = blk * 8 + srow;
      gload16(qk_b + 1024 + (size_t)(t * 64 + row) * 2048 + h * 64 + schunk * 8,
              (void*)(Ks[buf] + blk * 512));
      gload16(vT_b + (size_t)row * 1024 + t * 64 + schunk * 8,
              (void*)(Vts[buf] + blk * 512));
    }
  };

  stage(0, 0); // prologue stage of tile 0

  // Q fragments (row = lane&15 -> used as MFMA *second* operand, so qrow -> C col)
  f16x8 qf[4][2];
#pragma unroll
  for (int m = 0; m < 4; m++)
#pragma unroll
    for (int kk = 0; kk < 2; kk++) {
      int row = qbase + m * 16 + lr;
      int col = h * 64 + kk * 32 + lg * 8;
      qf[m][kk] = *(const f16x8*)(qk_b + (size_t)row * 2048 + col);
    }

  // per-lane q-row mask bits: bit m = mask of row qbase + m*16 + lr
  unsigned int mi4 = 0;
#pragma unroll
  for (int m = 0; m < 4; m++)
    mi4 |= (mp[qbase + m * 16 + lr] ? 1u : 0u) << m;

  const f32x4 zero4 = {0.f, 0.f, 0.f, 0.f};
  float mrun[4], lrun[4];   // per-lane state of row (m*16+lr)
  f32x4 oacc[4][4];
#pragma unroll
  for (int m = 0; m < 4; m++) {
    mrun[m] = -3e38f; lrun[m] = 0.f;
#pragma unroll
    for (int i = 0; i < 4; i++) oacc[m][i] = zero4;
  }

  __syncthreads(); // drains prologue stage (implicit vmcnt(0)) + Q loads

  for (int t = 0; t < 16; t++) {
    const int cur = t & 1;
    if (t < 15) stage(cur ^ 1, t + 1); // prefetch; latency hides under compute

    // S^T = K Q^T : st[n][m][ri] = S[qrow = m*16+lr][ktok = n*16+lg*4+ri]
    f32x4 st[4][4];
#pragma unroll
    for (int n = 0; n < 4; n++)
#pragma unroll
      for (int m = 0; m < 4; m++) st[n][m] = zero4;
#pragma unroll
    for (int kk = 0; kk < 2; kk++)
#pragma unroll
      for (int n = 0; n < 4; n++) {
        int krow = n * 16 + lr;
        int ch = (kk * 4 + lg) ^ (krow & 7);
        f16x8 kf = *(const f16x8*)&Ks[cur][krow * 64 + ch * 8];
#pragma unroll
        for (int m = 0; m < 4; m++)
          st[n][m] = __builtin_amdgcn_mfma_f32_16x16x32_f16(kf, qf[m][kk], st[n][m], 0, 0, 0);
      }

    // ktok-mask words: byte ri of mw[n] = mask[t*64 + n*16 + lg*4 + ri]
    unsigned int mw[4];
#pragma unroll
    for (int n = 0; n < 4; n++)
      mw[n] = *(const unsigned int*)(mp + t * 64 + n * 16 + lg * 4);

    // lane-local online softmax: each lane owns row (m*16+lr); 4 lg-copies merged
    // by 2 shuffles (xor 16, 32).
#pragma unroll
    for (int m = 0; m < 4; m++) {
      const bool rowok = (mi4 >> m) & 1;
      float sv[4][4];
      float vmax = -3e38f;
#pragma unroll
      for (int n = 0; n < 4; n++)
#pragma unroll
        for (int ri = 0; ri < 4; ri++) {
          float s = st[n][m][ri];
          bool ok = ((mw[n] >> (8 * ri)) & 255u) != 0u;
          s = rowok ? (ok ? s * 0.125f : -1e30f) : 0.f;
          sv[n][ri] = s;
          vmax = fmaxf(vmax, s);
        }
      vmax = fmaxf(vmax, __shfl_xor(vmax, 16));
      vmax = fmaxf(vmax, __shfl_xor(vmax, 32));
      float nm_ = fmaxf(mrun[m], vmax);
      float sc = __expf(mrun[m] - nm_); // 0 on first tile
      mrun[m] = nm_;
      float rs = 0.f;
      const int qr = m * 16 + lr;
#pragma unroll
      for (int n = 0; n < 4; n++) {
        f16x4 pk;
#pragma unroll
        for (int ri = 0; ri < 4; ri++) {
          float pp = __expf(sv[n][ri] - nm_);
          rs += pp;
          pk[ri] = (f16)pp;
        }
        const int col0 = n * 16 + lg * 4;
        const int swz = (col0 >> 3) ^ (qr & 7);
        *(f16x4*)&Ps[w][qr * 64 + swz * 8 + (col0 & 7)] = pk; // b64 write, 4 ktok
      }
      rs += __shfl_xor(rs, 16);
      rs += __shfl_xor(rs, 32);
      lrun[m] = lrun[m] * sc + rs;
      // oacc row (m*16+lg*4+ri) is owned by lane (lg*4+ri): broadcast its sc
      float scb[4];
#pragma unroll
      for (int ri = 0; ri < 4; ri++) scb[ri] = __shfl(sc, lg * 4 + ri);
#pragma unroll
      for (int dn = 0; dn < 4; dn++)
#pragma unroll
        for (int ri = 0; ri < 4; ri++) oacc[m][dn][ri] *= scb[ri];
    }
    asm volatile("s_waitcnt lgkmcnt(0)" ::: "memory");
    __builtin_amdgcn_sched_barrier(0);

    // O += P V   (A = P from Ps, B = rows of V^T from Vts)
#pragma unroll
    for (int kk = 0; kk < 2; kk++) {
      f16x8 pa[4];
#pragma unroll
      for (int m = 0; m < 4; m++) {
        int qr = m * 16 + lr;
        int ch = (kk * 4 + lg) ^ (qr & 7);
        pa[m] = *(const f16x8*)&Ps[w][qr * 64 + ch * 8];
      }
#pragma unroll
      for (int dn = 0; dn < 4; dn++) {
        int vrow = dn * 16 + lr;
        int ch = (kk * 4 + lg) ^ (vrow & 7);
        f16x8 vf = *(const f16x8*)&Vts[cur][vrow * 64 + ch * 8];
#pragma unroll
        for (int m = 0; m < 4; m++)
          oacc[m][dn] = __builtin_amdgcn_mfma_f32_16x16x32_f16(pa[m], vf, oacc[m][dn], 0, 0, 0);
      }
    }
    // single barrier per tile: implicit vmcnt(0) drains stage(t+1) AFTER a full
    // compute phase; lgkmcnt(0) retires LDS reads of buf[cur] (WAR-safe).
    __syncthreads();
  }

  // epilogue: O / l -> ob f16 (broadcast lrun from owner lane lg*4+ri)
#pragma unroll
  for (int m = 0; m < 4; m++) {
    float lb[4];
#pragma unroll
    for (int ri = 0; ri < 4; ri++) lb[ri] = __shfl(lrun[m], lg * 4 + ri);
#pragma unroll
    for (int dn = 0; dn < 4; dn++)
#pragma unroll
      for (int ri = 0; ri < 4; ri++) {
        int qg = qbase + m * 16 + lg * 4 + ri;
        float o = oacc[m][dn][ri] / lb[ri];
        ob[(size_t)(b * 1024 + qg) * 1024 + h * 64 + dn * 16 + lr] = (f16)o;
      }
  }
}

// ---------- host ----------
extern "C" void kernel_launch(void* const* d_in, const int* in_sizes, int n_in,
                              void* d_out, int out_size, void* d_ws, size_t ws_size,
                              hipStream_t stream) {
  const float* x     = (const float*)d_in[0];
  const void*  mask  = d_in[1];
  const float* w_qkv = (const float*)d_in[2];
  const float* w_out = (const float*)d_in[3];
  const float* b_out = (const float*)d_in[4];
  float* out  = (float*)d_out;           // [8192][1024]
  float* attn = out + 8388608;           // [8][1024][1024]

  char* ws = (char*)d_ws;
  f16* xb    = (f16*)(ws);                    // [8192][1024]          16.78 MB (dead after gemm8<0>)
  f16* wqkvT = (f16*)(ws + 16777216);         // [3072][1024]           6.29 MB
  f16* woutT = (f16*)(ws + 23068672);         // [1024][1024]           2.10 MB
  f16* qkb   = (f16*)(ws + 25165824);         // [8][1024][2048]       33.55 MB
  f16* vTb   = (f16*)(ws + 58720256);         // [8][1024 d][1024 n]   16.78 MB
  f16* ob    = xb;                            // aliases xb (lifetimes disjoint)
  unsigned char* mpad = (unsigned char*)(ws + 75497472); // [8][1024]

  cast_f16<<<8192, 256, 0, stream>>>(x, xb, 2097152);
  transpose_cast<<<dim3(48, 16), 256, 0, stream>>>(w_qkv, wqkvT, 1024, 3072);
  transpose_cast<<<dim3(16, 16), 256, 0, stream>>>(w_out, woutT, 1024, 1024);
  prep_mask<<<32, 256, 0, stream>>>(mask, mpad);

  // qkv = x @ w_qkv  (M=8192, N=3072, K=1024): 768 blocks = 3.0/CU
  gemm8<0><<<dim3(24, 32), 512, 0, stream>>>(xb, 1024, 0, wqkvT, 1024, 0,
                                             nullptr, 0, nullptr, qkb, vTb, 3072);
  // pooled S = q_ k_^T * SCALE_  (per batch, M=N=K=1024): 256 blocks = 1.0/CU
  gemm8<1><<<dim3(8, 4, 8), 512, 0, stream>>>(qkb, 2048, 2097152, qkb + 1024, 2048, 2097152,
                                              attn, 1048576, nullptr, nullptr, nullptr, 1024);
  softmax_rows<<<8192, 256, 0, stream>>>(attn);

  flash_kernel<<<dim3(128, 4), 256, 0, stream>>>(qkb, vTb, mpad, ob);

  // out = ob @ w_out + b_out  (M=8192, N=1024, K=1024): 256 blocks = 1.0/CU
  gemm8<2><<<dim3(8, 32), 512, 0, stream>>>(ob, 1024, 0, woutT, 1024, 0,
                                            out, 0, b_out, nullptr, nullptr, 1024);
}